// Round 9
// baseline (179.779 us; speedup 1.0000x reference)
//
#include <hip/hip_runtime.h>

// ---------------------------------------------------------------------------
// VisualContrastiveLoss on MI355X
// loss = C + mean_i log(Z_i) - mean_i sim[i, lab_i],  C = 1/0.07
//   Z_i = sum_j exp(sim_ij - C)   (fixed shift: dots bounded by 1)
//   sim = (f f^T)/0.07, f = row-normalized visual_feat
// R9: R6 structure (64x64 wave tile, launch_bounds(256,2), unroll-1) +
//     (a) grid (64,16), jt=4 -> 1024 blocks so the 3-blocks/CU residency the
//         R6 binary already permits is actually used (R8 lesson: occupancy
//         was grid-limited; constraining regs only caused spill);
//     (b) de-interleaved LDS granules: slot s of row r holds global granule
//         h(s^(r&7)), h(u)=2(u&3)+(u>>2), so frag reads use (q)^swz and
//         (q+4)^swz -- R2's measured-zero-conflict pattern (R6's adjacent-
//         pair reads measured 4 conflict-cycles per ds_read_b128).
// ---------------------------------------------------------------------------

typedef int i32x8 __attribute__((ext_vector_type(8)));
typedef float f32x4 __attribute__((ext_vector_type(4)));

#define B_N 8192
#define D_K 512
#define ROWB 512   // bytes per fp8 row
#define NBLK 1024  // sim grid size (64 x 16)
#define INVT 14.285714285714286f
// (1/0.07) * log2(e)
#define SCALE_LOG2 20.609929155556622f

#define AGENT_LOAD(p) __hip_atomic_load((p), __ATOMIC_RELAXED, __HIP_MEMORY_SCOPE_AGENT)
#define AGENT_STORE(p, v) __hip_atomic_store((p), (v), __ATOMIC_RELAXED, __HIP_MEMORY_SCOPE_AGENT)

static __device__ __forceinline__ void load16_to_lds(const void* g, void* l) {
  __builtin_amdgcn_global_load_lds(
      (const __attribute__((address_space(1))) unsigned int*)g,
      (__attribute__((address_space(3))) unsigned int*)l, 16, 0, 0);
}

// ---- K1: 4 waves/block, one wave per row; normalize fp32 -> fp8 e4m3 --------
// Also zeroes Z and the done-counter (ws is poisoned before every launch).
__global__ __launch_bounds__(256)
void norm_kernel(const float* __restrict__ x,
                 unsigned char* __restrict__ fQ,
                 float* __restrict__ Z,
                 unsigned int* __restrict__ cnt) {
  const int row = blockIdx.x * 4 + (threadIdx.x >> 6);
  const int lane = threadIdx.x & 63;
  const float4* xr = (const float4*)(x + (size_t)row * D_K);
  float4 a = xr[2 * lane];
  float4 b = xr[2 * lane + 1];
  float s = a.x * a.x + a.y * a.y + a.z * a.z + a.w * a.w +
            b.x * b.x + b.y * b.y + b.z * b.z + b.w * b.w;
#pragma unroll
  for (int off = 1; off < 64; off <<= 1) s += __shfl_xor(s, off);
  const float inv = 1.0f / fmaxf(sqrtf(s), 1e-12f);
  int lo = 0, hi = 0;
  lo = __builtin_amdgcn_cvt_pk_fp8_f32(a.x * inv, a.y * inv, lo, false);
  lo = __builtin_amdgcn_cvt_pk_fp8_f32(a.z * inv, a.w * inv, lo, true);
  hi = __builtin_amdgcn_cvt_pk_fp8_f32(b.x * inv, b.y * inv, hi, false);
  hi = __builtin_amdgcn_cvt_pk_fp8_f32(b.z * inv, b.w * inv, hi, true);
  int2 p; p.x = lo; p.y = hi;
  ((int2*)(fQ + (size_t)row * ROWB))[lane] = p;
  if (lane == 0) Z[row] = 0.0f;
  if (blockIdx.x == 0 && threadIdx.x == 0) cnt[0] = 0u;
}

// ---- K2: fused fp8 similarity + softmax-denominator + final loss ------------
// grid (64, 16): blockIdx.x -> 128-row tile, blockIdx.y -> 512-col j-range
// (4 jt of 128 cols). 4 waves 2x2; wave owns 64x64 C via 4x4 frags of
// 16x16x128 MX-fp8 MFMA (scale=1). K staged in 4 chunks of 128 B/row.
// LDS granule layout: slot s of row r holds global granule h(s^(r&7)),
// h(u)=2(u&3)+(u>>2) -> frag reads at slots (q)^swz / (q+4)^swz reconstruct
// global granules 2q,2q+1 with the R2-verified conflict-free bank pattern.
// unroll-1 on jt/kk contains the unroller (R6 lesson: hoisting caused spill).
// Last block to finish (device-scope counter) computes the final loss.
__global__ __launch_bounds__(256, 2)
void sim_kernel(const unsigned char* __restrict__ fQ,
                float* __restrict__ Z, float* __restrict__ T01,
                float* __restrict__ D,
                const int* __restrict__ ids,
                const int* __restrict__ anchor,
                unsigned int* __restrict__ cnt,
                float* __restrict__ out) {
  __shared__ unsigned char ldsA[128 * 128];   // 16 KB
  __shared__ unsigned char ldsB[128 * 128];   // 16 KB
  __shared__ unsigned int s_last;

  const int tid = threadIdx.x;
  const int lane = tid & 63;
  const int w = tid >> 6;
  const int wm = w & 1;       // wave row strip (0/1) -> rows wm*64..
  const int wn = w >> 1;      // wave col strip (0/1) -> cols wn*64..
  const int bx = blockIdx.x, by = blockIdx.y;
  const int I0 = bx * 128;
  const int Jbase = by * 512;

  // staging lane geometry: 8 rows x 8 slots(16B) per instruction.
  // slot b of row a sources global granule h(b^a), h(u)=2(u&3)+(u>>2).
  const int srow = lane >> 3;                 // 0..7
  const int sb = lane & 7;                    // dest slot
  const int su = sb ^ srow;
  const int sg = 2 * (su & 3) + (su >> 2);    // source granule
  const size_t sOff = (size_t)srow * ROWB + sg * 16;  // bytes

  // fragment-read lane geometry
  const int fr = lane & 15;   // M/N index within 16
  const int q = lane >> 4;    // quad -> k chunk of 32B
  const int swz = fr & 7;     // row&7 of the frag row

  // precomputed LDS frag base pointers (byte addresses)
  const unsigned char* raBase = ldsA + (wm * 64 + fr) * 128;
  const unsigned char* rbBase = ldsB + (wn * 64 + fr) * 128;
  const int off0 = (q ^ swz) * 16;        // slot holding granule 2q
  const int off1 = ((q + 4) ^ swz) * 16;  // slot holding granule 2q+1

  float Zp[4][4];
#pragma unroll
  for (int m = 0; m < 4; ++m)
#pragma unroll
    for (int r = 0; r < 4; ++r) Zp[m][r] = 0.0f;

#pragma unroll 1
  for (int jt = 0; jt < 4; ++jt) {
    const int J0 = Jbase + jt * 128;
    f32x4 acc[4][4];
#pragma unroll
    for (int m = 0; m < 4; ++m)
#pragma unroll
      for (int n = 0; n < 4; ++n) acc[m][n] = (f32x4){0.f, 0.f, 0.f, 0.f};

#pragma unroll 1
    for (int kk = 0; kk < 4; ++kk) {
      const int k0 = kk * 128;  // byte offset into row
      {  // A: 128 rows, wave stages rows w*32..+31 (4 instrs)
        const unsigned char* gA = fQ + (size_t)(I0 + w * 32) * ROWB + k0 + sOff;
        unsigned char* lA = ldsA + (w * 32) * 128;
#pragma unroll
        for (int rr = 0; rr < 32; rr += 8)
          load16_to_lds(gA + (size_t)rr * ROWB, lA + rr * 128);
      }
      {  // B: 128 rows, wave stages rows w*32..+31 (4 instrs)
        const unsigned char* gB = fQ + (size_t)(J0 + w * 32) * ROWB + k0 + sOff;
        unsigned char* lB = ldsB + (w * 32) * 128;
#pragma unroll
        for (int rr = 0; rr < 32; rr += 8)
          load16_to_lds(gB + (size_t)rr * ROWB, lB + rr * 128);
      }
      __syncthreads();

      i32x8 bv[4];
#pragma unroll
      for (int n = 0; n < 4; ++n) {
        const unsigned char* rb = rbBase + n * 16 * 128;
        int4 r0 = *(const int4*)(rb + off0);
        int4 r1 = *(const int4*)(rb + off1);
        bv[n] = (i32x8){r0.x, r0.y, r0.z, r0.w, r1.x, r1.y, r1.z, r1.w};
      }
#pragma unroll
      for (int mh = 0; mh < 2; ++mh) {  // m-split: av[2] live, not av[4]
        i32x8 av[2];
#pragma unroll
        for (int m = 0; m < 2; ++m) {
          const unsigned char* ra = raBase + (mh * 2 + m) * 16 * 128;
          int4 r0 = *(const int4*)(ra + off0);
          int4 r1 = *(const int4*)(ra + off1);
          av[m] = (i32x8){r0.x, r0.y, r0.z, r0.w, r1.x, r1.y, r1.z, r1.w};
        }
#pragma unroll
        for (int m = 0; m < 2; ++m)
#pragma unroll
          for (int n = 0; n < 4; ++n)
            acc[mh * 2 + m][n] = __builtin_amdgcn_mfma_scale_f32_16x16x128_f8f6f4(
                av[m], bv[n], acc[mh * 2 + m][n], 0, 0, 0, 127, 0, 127);
      }
      __syncthreads();
    }

    // capture sim[:,0] and sim[:,1] (cols 0,1: j-tile 0, wn==0, n==0, fr<2)
    if (by == 0 && jt == 0 && wn == 0 && fr < 2) {
#pragma unroll
      for (int m = 0; m < 4; ++m)
#pragma unroll
        for (int r = 0; r < 4; ++r) {
          const int row = I0 + wm * 64 + m * 16 + q * 4 + r;
          AGENT_STORE(&T01[row * 2 + fr], acc[m][0][r] * INVT);
        }
    }

    // capture the computed diagonal dot (for exact-diag correction)
    if (by == (bx >> 2) && jt == (bx & 3)) {
#pragma unroll
      for (int m = 0; m < 4; ++m)
#pragma unroll
        for (int n = 0; n < 4; ++n) {
          const int col = J0 + wn * 64 + n * 16 + fr;
#pragma unroll
          for (int r = 0; r < 4; ++r) {
            const int row = I0 + wm * 64 + m * 16 + q * 4 + r;
            if (row == col) AGENT_STORE(&D[row], acc[m][n][r]);
          }
        }
    }

    // Z partials: exp((dot-1)/T) summed over this wave's 64 cols
#pragma unroll
    for (int m = 0; m < 4; ++m)
#pragma unroll
      for (int n = 0; n < 4; ++n)
#pragma unroll
        for (int r = 0; r < 4; ++r)
          Zp[m][r] += exp2f((acc[m][n][r] - 1.0f) * SCALE_LOG2);
  }

  // reduce Zp across the 16 col-lanes (low 4 lane bits), then atomicAdd
#pragma unroll
  for (int m = 0; m < 4; ++m)
#pragma unroll
    for (int r = 0; r < 4; ++r) {
      float v = Zp[m][r];
      v += __shfl_xor(v, 1);
      v += __shfl_xor(v, 2);
      v += __shfl_xor(v, 4);
      v += __shfl_xor(v, 8);
      if (fr == 0) atomicAdd(&Z[I0 + wm * 64 + m * 16 + q * 4 + r], v);
    }

  // ---- last-block-done: final loss reduction (no spin; graph-safe) ----------
  __syncthreads();               // all waves' atomics issued
  __threadfence();               // release: make Z/T01/D visible device-wide
  if (tid == 0) s_last = atomicAdd(cnt, 1u);
  __syncthreads();
  if (s_last != NBLK - 1) return;
  __threadfence();               // acquire side

  const int anchor_id = ids[anchor[0]];
  const int sameLast = (ids[B_N - 1] == anchor_id);
  const int samePrev = (ids[B_N - 2] == anchor_id);
  float sum = 0.0f;
  // 32 rows/thread in batches of 4; independent loads so vmcnt overlaps.
#pragma unroll 1
  for (int ib = 0; ib < 8; ++ib) {
    int i[4];
    float z[4], d[4], t0[4], t1[4];
    int id[4];
#pragma unroll
    for (int u = 0; u < 4; ++u) {
      i[u] = (ib * 4 + u) * 256 + tid;
      z[u] = AGENT_LOAD(&Z[i[u]]);
      d[u] = AGENT_LOAD(&D[i[u]]);
      t0[u] = AGENT_LOAD(&T01[i[u] * 2 + 0]);
      t1[u] = AGENT_LOAD(&T01[i[u] * 2 + 1]);
      id[u] = ids[i[u]];
    }
#pragma unroll
    for (int u = 0; u < 4; ++u) {
      const int same_i = (id[u] == anchor_id);
      const int lab =
          (i[u] < B_N - 1) ? (same_i & sameLast) : (sameLast & samePrev);
      const float tt = lab ? t1[u] : t0[u];
      // replace quantized diag contribution with the exact value exp(0)=1
      const float Zc = z[u] - exp2f((d[u] - 1.0f) * SCALE_LOG2) + 1.0f;
      sum += tt - (INVT + logf(Zc));
    }
  }
  float* red = (float*)ldsA;     // reuse LDS for the block reduction
  red[tid] = sum;
  __syncthreads();
  for (int off = 128; off > 0; off >>= 1) {
    if (tid < off) red[tid] += red[tid + off];
    __syncthreads();
  }
  if (tid == 0) out[0] = -red[0] / (float)B_N;
}

// ---------------------------------------------------------------------------
extern "C" void kernel_launch(void* const* d_in, const int* in_sizes, int n_in,
                              void* d_out, int out_size, void* d_ws, size_t ws_size,
                              hipStream_t stream) {
  const float* x = (const float*)d_in[0];
  const int* ids = (const int*)d_in[1];
  const int* anchor = (const int*)d_in[2];
  float* out = (float*)d_out;

  unsigned char* fQ = (unsigned char*)d_ws;                    // 4 MB fp8
  float* Z = (float*)((char*)d_ws + (size_t)B_N * ROWB);       // 32 KB
  float* T01 = Z + B_N;                                        // 64 KB
  float* D = T01 + 2 * B_N;                                    // 32 KB
  unsigned int* cnt = (unsigned int*)(D + B_N);                // 4 B

  norm_kernel<<<B_N / 4, 256, 0, stream>>>(x, fQ, Z, cnt);
  sim_kernel<<<dim3(64, 16), 256, 0, stream>>>(fQ, Z, T01, D, ids, anchor, cnt, out);
}

// Round 10
// 153.859 us; speedup vs baseline: 1.1685x; 1.1685x over previous
//
#include <hip/hip_runtime.h>

// ---------------------------------------------------------------------------
// VisualContrastiveLoss on MI355X
// loss = C + mean_i log(Z_i) - mean_i sim[i, lab_i],  C = 1/0.07
//   Z_i = sum_j exp(sim_ij - C)   (fixed shift: dots bounded by 1)
//   sim = (f f^T)/0.07, f = row-normalized visual_feat
// R10: exact R6 shape (grid (64,8), jt=8, 64x64 wave tile, lb(256,2),
//     unroll-1) + ONLY the R9 conflict-free LDS granule layout (isolated
//     variable; R9 confounded swizzle with grid/jt and regressed 2x from
//     the grid/jt half). Fused last-block tail kept (hot-path neutral).
//     LDS layout: slot s of row r holds global granule h(s^(r&7)),
//     h(u)=2(u&3)+(u>>2); frag reads at slots (q)^swz,(q+4)^swz reconstruct
//     granules 2q,2q+1 with R2's measured-zero-conflict bank pattern.
// ---------------------------------------------------------------------------

typedef int i32x8 __attribute__((ext_vector_type(8)));
typedef float f32x4 __attribute__((ext_vector_type(4)));

#define B_N 8192
#define D_K 512
#define ROWB 512  // bytes per fp8 row
#define NBLK 512  // sim grid size (64 x 8)
#define INVT 14.285714285714286f
// (1/0.07) * log2(e)
#define SCALE_LOG2 20.609929155556622f

#define AGENT_LOAD(p) __hip_atomic_load((p), __ATOMIC_RELAXED, __HIP_MEMORY_SCOPE_AGENT)
#define AGENT_STORE(p, v) __hip_atomic_store((p), (v), __ATOMIC_RELAXED, __HIP_MEMORY_SCOPE_AGENT)

static __device__ __forceinline__ void load16_to_lds(const void* g, void* l) {
  __builtin_amdgcn_global_load_lds(
      (const __attribute__((address_space(1))) unsigned int*)g,
      (__attribute__((address_space(3))) unsigned int*)l, 16, 0, 0);
}

// ---- K1: 4 waves/block, one wave per row; normalize fp32 -> fp8 e4m3 --------
// Also zeroes Z and the done-counter (ws is poisoned before every launch).
__global__ __launch_bounds__(256)
void norm_kernel(const float* __restrict__ x,
                 unsigned char* __restrict__ fQ,
                 float* __restrict__ Z,
                 unsigned int* __restrict__ cnt) {
  const int row = blockIdx.x * 4 + (threadIdx.x >> 6);
  const int lane = threadIdx.x & 63;
  const float4* xr = (const float4*)(x + (size_t)row * D_K);
  float4 a = xr[2 * lane];
  float4 b = xr[2 * lane + 1];
  float s = a.x * a.x + a.y * a.y + a.z * a.z + a.w * a.w +
            b.x * b.x + b.y * b.y + b.z * b.z + b.w * b.w;
#pragma unroll
  for (int off = 1; off < 64; off <<= 1) s += __shfl_xor(s, off);
  const float inv = 1.0f / fmaxf(sqrtf(s), 1e-12f);
  int lo = 0, hi = 0;
  lo = __builtin_amdgcn_cvt_pk_fp8_f32(a.x * inv, a.y * inv, lo, false);
  lo = __builtin_amdgcn_cvt_pk_fp8_f32(a.z * inv, a.w * inv, lo, true);
  hi = __builtin_amdgcn_cvt_pk_fp8_f32(b.x * inv, b.y * inv, hi, false);
  hi = __builtin_amdgcn_cvt_pk_fp8_f32(b.z * inv, b.w * inv, hi, true);
  int2 p; p.x = lo; p.y = hi;
  ((int2*)(fQ + (size_t)row * ROWB))[lane] = p;
  if (lane == 0) Z[row] = 0.0f;
  if (blockIdx.x == 0 && threadIdx.x == 0) cnt[0] = 0u;
}

// ---- K2: fused fp8 similarity + softmax-denominator + final loss ------------
// grid (64, 8): blockIdx.x -> 128-row tile, blockIdx.y -> 1024-col j-range
// (8 jt of 128 cols). 4 waves 2x2; wave owns 64x64 C via 4x4 frags of
// 16x16x128 MX-fp8 MFMA (scale=1). K staged in 4 chunks of 128 B/row.
// unroll-1 on jt/kk contains the unroller (R6 lesson: hoisting caused spill).
// Last block to finish (device-scope counter) computes the final loss.
__global__ __launch_bounds__(256, 2)
void sim_kernel(const unsigned char* __restrict__ fQ,
                float* __restrict__ Z, float* __restrict__ T01,
                float* __restrict__ D,
                const int* __restrict__ ids,
                const int* __restrict__ anchor,
                unsigned int* __restrict__ cnt,
                float* __restrict__ out) {
  __shared__ unsigned char ldsA[128 * 128];   // 16 KB
  __shared__ unsigned char ldsB[128 * 128];   // 16 KB
  __shared__ unsigned int s_last;

  const int tid = threadIdx.x;
  const int lane = tid & 63;
  const int w = tid >> 6;
  const int wm = w & 1;       // wave row strip (0/1) -> rows wm*64..
  const int wn = w >> 1;      // wave col strip (0/1) -> cols wn*64..
  const int bx = blockIdx.x, by = blockIdx.y;
  const int I0 = bx * 128;
  const int Jbase = by * 1024;

  // staging lane geometry: 8 rows x 8 slots(16B) per instruction.
  // slot b of row a sources global granule h(b^a), h(u)=2(u&3)+(u>>2).
  const int srow = lane >> 3;                 // 0..7
  const int sb = lane & 7;                    // dest slot
  const int su = sb ^ srow;
  const int sg = 2 * (su & 3) + (su >> 2);    // source granule
  const size_t sOff = (size_t)srow * ROWB + sg * 16;  // bytes

  // fragment-read lane geometry
  const int fr = lane & 15;   // M/N index within 16
  const int q = lane >> 4;    // quad -> k chunk of 32B
  const int swz = fr & 7;     // row&7 of the frag row

  // precomputed LDS frag base pointers (byte addresses)
  const unsigned char* raBase = ldsA + (wm * 64 + fr) * 128;
  const unsigned char* rbBase = ldsB + (wn * 64 + fr) * 128;
  const int off0 = (q ^ swz) * 16;        // slot holding granule 2q
  const int off1 = ((q + 4) ^ swz) * 16;  // slot holding granule 2q+1

  float Zp[4][4];
#pragma unroll
  for (int m = 0; m < 4; ++m)
#pragma unroll
    for (int r = 0; r < 4; ++r) Zp[m][r] = 0.0f;

#pragma unroll 1
  for (int jt = 0; jt < 8; ++jt) {
    const int J0 = Jbase + jt * 128;
    f32x4 acc[4][4];
#pragma unroll
    for (int m = 0; m < 4; ++m)
#pragma unroll
      for (int n = 0; n < 4; ++n) acc[m][n] = (f32x4){0.f, 0.f, 0.f, 0.f};

#pragma unroll 1
    for (int kk = 0; kk < 4; ++kk) {
      const int k0 = kk * 128;  // byte offset into row
      {  // A: 128 rows, wave stages rows w*32..+31 (4 instrs)
        const unsigned char* gA = fQ + (size_t)(I0 + w * 32) * ROWB + k0 + sOff;
        unsigned char* lA = ldsA + (w * 32) * 128;
#pragma unroll
        for (int rr = 0; rr < 32; rr += 8)
          load16_to_lds(gA + (size_t)rr * ROWB, lA + rr * 128);
      }
      {  // B: 128 rows, wave stages rows w*32..+31 (4 instrs)
        const unsigned char* gB = fQ + (size_t)(J0 + w * 32) * ROWB + k0 + sOff;
        unsigned char* lB = ldsB + (w * 32) * 128;
#pragma unroll
        for (int rr = 0; rr < 32; rr += 8)
          load16_to_lds(gB + (size_t)rr * ROWB, lB + rr * 128);
      }
      __syncthreads();

      i32x8 bv[4];
#pragma unroll
      for (int n = 0; n < 4; ++n) {
        const unsigned char* rb = rbBase + n * 16 * 128;
        int4 r0 = *(const int4*)(rb + off0);
        int4 r1 = *(const int4*)(rb + off1);
        bv[n] = (i32x8){r0.x, r0.y, r0.z, r0.w, r1.x, r1.y, r1.z, r1.w};
      }
#pragma unroll
      for (int mh = 0; mh < 2; ++mh) {  // m-split: av[2] live, not av[4]
        i32x8 av[2];
#pragma unroll
        for (int m = 0; m < 2; ++m) {
          const unsigned char* ra = raBase + (mh * 2 + m) * 16 * 128;
          int4 r0 = *(const int4*)(ra + off0);
          int4 r1 = *(const int4*)(ra + off1);
          av[m] = (i32x8){r0.x, r0.y, r0.z, r0.w, r1.x, r1.y, r1.z, r1.w};
        }
#pragma unroll
        for (int m = 0; m < 2; ++m)
#pragma unroll
          for (int n = 0; n < 4; ++n)
            acc[mh * 2 + m][n] = __builtin_amdgcn_mfma_scale_f32_16x16x128_f8f6f4(
                av[m], bv[n], acc[mh * 2 + m][n], 0, 0, 0, 127, 0, 127);
      }
      __syncthreads();
    }

    // capture sim[:,0] and sim[:,1] (cols 0,1: j-tile 0, wn==0, n==0, fr<2)
    if (by == 0 && jt == 0 && wn == 0 && fr < 2) {
#pragma unroll
      for (int m = 0; m < 4; ++m)
#pragma unroll
        for (int r = 0; r < 4; ++r) {
          const int row = I0 + wm * 64 + m * 16 + q * 4 + r;
          AGENT_STORE(&T01[row * 2 + fr], acc[m][0][r] * INVT);
        }
    }

    // capture the computed diagonal dot (for exact-diag correction)
    if (by == (bx >> 3) && jt == (bx & 7)) {
#pragma unroll
      for (int m = 0; m < 4; ++m)
#pragma unroll
        for (int n = 0; n < 4; ++n) {
          const int col = J0 + wn * 64 + n * 16 + fr;
#pragma unroll
          for (int r = 0; r < 4; ++r) {
            const int row = I0 + wm * 64 + m * 16 + q * 4 + r;
            if (row == col) AGENT_STORE(&D[row], acc[m][n][r]);
          }
        }
    }

    // Z partials: exp((dot-1)/T) summed over this wave's 64 cols
#pragma unroll
    for (int m = 0; m < 4; ++m)
#pragma unroll
      for (int n = 0; n < 4; ++n)
#pragma unroll
        for (int r = 0; r < 4; ++r)
          Zp[m][r] += exp2f((acc[m][n][r] - 1.0f) * SCALE_LOG2);
  }

  // reduce Zp across the 16 col-lanes (low 4 lane bits), then atomicAdd
#pragma unroll
  for (int m = 0; m < 4; ++m)
#pragma unroll
    for (int r = 0; r < 4; ++r) {
      float v = Zp[m][r];
      v += __shfl_xor(v, 1);
      v += __shfl_xor(v, 2);
      v += __shfl_xor(v, 4);
      v += __shfl_xor(v, 8);
      if (fr == 0) atomicAdd(&Z[I0 + wm * 64 + m * 16 + q * 4 + r], v);
    }

  // ---- last-block-done: final loss reduction (no spin; graph-safe) ----------
  __syncthreads();               // all waves' atomics issued
  __threadfence();               // release: make Z/T01/D visible device-wide
  if (tid == 0) s_last = atomicAdd(cnt, 1u);
  __syncthreads();
  if (s_last != NBLK - 1) return;
  __threadfence();               // acquire side

  const int anchor_id = ids[anchor[0]];
  const int sameLast = (ids[B_N - 1] == anchor_id);
  const int samePrev = (ids[B_N - 2] == anchor_id);
  float sum = 0.0f;
  // 32 rows/thread in batches of 4; independent loads so vmcnt overlaps.
#pragma unroll 1
  for (int ib = 0; ib < 8; ++ib) {
    int i[4];
    float z[4], d[4], t0[4], t1[4];
    int id[4];
#pragma unroll
    for (int u = 0; u < 4; ++u) {
      i[u] = (ib * 4 + u) * 256 + tid;
      z[u] = AGENT_LOAD(&Z[i[u]]);
      d[u] = AGENT_LOAD(&D[i[u]]);
      t0[u] = AGENT_LOAD(&T01[i[u] * 2 + 0]);
      t1[u] = AGENT_LOAD(&T01[i[u] * 2 + 1]);
      id[u] = ids[i[u]];
    }
#pragma unroll
    for (int u = 0; u < 4; ++u) {
      const int same_i = (id[u] == anchor_id);
      const int lab =
          (i[u] < B_N - 1) ? (same_i & sameLast) : (sameLast & samePrev);
      const float tt = lab ? t1[u] : t0[u];
      // replace quantized diag contribution with the exact value exp(0)=1
      const float Zc = z[u] - exp2f((d[u] - 1.0f) * SCALE_LOG2) + 1.0f;
      sum += tt - (INVT + logf(Zc));
    }
  }
  float* red = (float*)ldsA;     // reuse LDS for the block reduction
  red[tid] = sum;
  __syncthreads();
  for (int off = 128; off > 0; off >>= 1) {
    if (tid < off) red[tid] += red[tid + off];
    __syncthreads();
  }
  if (tid == 0) out[0] = -red[0] / (float)B_N;
}

// ---------------------------------------------------------------------------
extern "C" void kernel_launch(void* const* d_in, const int* in_sizes, int n_in,
                              void* d_out, int out_size, void* d_ws, size_t ws_size,
                              hipStream_t stream) {
  const float* x = (const float*)d_in[0];
  const int* ids = (const int*)d_in[1];
  const int* anchor = (const int*)d_in[2];
  float* out = (float*)d_out;

  unsigned char* fQ = (unsigned char*)d_ws;                    // 4 MB fp8
  float* Z = (float*)((char*)d_ws + (size_t)B_N * ROWB);       // 32 KB
  float* T01 = Z + B_N;                                        // 64 KB
  float* D = T01 + 2 * B_N;                                    // 32 KB
  unsigned int* cnt = (unsigned int*)(D + B_N);                // 4 B

  norm_kernel<<<B_N / 4, 256, 0, stream>>>(x, fQ, Z, cnt);
  sim_kernel<<<dim3(64, 8), 256, 0, stream>>>(fQ, Z, T01, D, ids, anchor, cnt, out);
}

// Round 11
// 118.923 us; speedup vs baseline: 1.5117x; 1.2938x over previous
//
#include <hip/hip_runtime.h>

// ---------------------------------------------------------------------------
// VisualContrastiveLoss on MI355X
// loss = C + mean_i log(Z_i) - mean_i sim[i, lab_i],  C = 1/0.07
//   Z_i = sum_j exp(sim_ij - C)   (fixed shift: dots bounded by 1)
//   sim = (f f^T)/0.07, f = row-normalized visual_feat
// R11: 3-kernel structure restored. R7/R8/R10 all paid ~+37us for the fused
//     last-block tail (per-block device-scope __threadfence -> L2 writeback
//     on 8-XCD gfx950); cross-kernel visibility via stream ordering is free.
//     Kept: R10's zero-conflict LDS granule layout (slot s of row r holds
//     global granule h(s^(r&7)), h(u)=2(u&3)+(u>>2)). New: A staged ONCE per
//     block (64KB, 4 chunk-planes); kk loop stages only B -> half the
//     global_load_lds per barrier. LDS 80KB/block = 2 blocks/CU exactly.
// ---------------------------------------------------------------------------

typedef int i32x8 __attribute__((ext_vector_type(8)));
typedef float f32x4 __attribute__((ext_vector_type(4)));

#define B_N 8192
#define D_K 512
#define ROWB 512  // bytes per fp8 row
#define INVT 14.285714285714286f
// (1/0.07) * log2(e)
#define SCALE_LOG2 20.609929155556622f

static __device__ __forceinline__ void load16_to_lds(const void* g, void* l) {
  __builtin_amdgcn_global_load_lds(
      (const __attribute__((address_space(1))) unsigned int*)g,
      (__attribute__((address_space(3))) unsigned int*)l, 16, 0, 0);
}

// ---- K1: 4 waves/block, one wave per row; normalize fp32 -> fp8 e4m3 --------
// Also zeroes Z (ws is poisoned before every launch).
__global__ __launch_bounds__(256)
void norm_kernel(const float* __restrict__ x,
                 unsigned char* __restrict__ fQ,
                 float* __restrict__ Z) {
  const int row = blockIdx.x * 4 + (threadIdx.x >> 6);
  const int lane = threadIdx.x & 63;
  const float4* xr = (const float4*)(x + (size_t)row * D_K);
  float4 a = xr[2 * lane];
  float4 b = xr[2 * lane + 1];
  float s = a.x * a.x + a.y * a.y + a.z * a.z + a.w * a.w +
            b.x * b.x + b.y * b.y + b.z * b.z + b.w * b.w;
#pragma unroll
  for (int off = 1; off < 64; off <<= 1) s += __shfl_xor(s, off);
  const float inv = 1.0f / fmaxf(sqrtf(s), 1e-12f);
  int lo = 0, hi = 0;
  lo = __builtin_amdgcn_cvt_pk_fp8_f32(a.x * inv, a.y * inv, lo, false);
  lo = __builtin_amdgcn_cvt_pk_fp8_f32(a.z * inv, a.w * inv, lo, true);
  hi = __builtin_amdgcn_cvt_pk_fp8_f32(b.x * inv, b.y * inv, hi, false);
  hi = __builtin_amdgcn_cvt_pk_fp8_f32(b.z * inv, b.w * inv, hi, true);
  int2 p; p.x = lo; p.y = hi;
  ((int2*)(fQ + (size_t)row * ROWB))[lane] = p;
  if (lane == 0) Z[row] = 0.0f;
}

// ---- K2: fused fp8 similarity + partial softmax-denominator -----------------
// grid (64, 8): blockIdx.x -> 128-row tile, blockIdx.y -> 1024-col j-range
// (8 jt of 128 cols). 4 waves 2x2; wave owns 64x64 C via 4x4 frags of
// 16x16x128 MX-fp8 MFMA (scale=1). A (128 rows x full K) staged once into
// 4 chunk-planes of 16KB; B staged per kk (16KB). Granule layout per 128B
// chunk: slot s of row r holds global granule h(s^(r&7)), h(u)=2(u&3)+(u>>2);
// frag reads at slots (q)^swz,(q+4)^swz -> granules 2q,2q+1, zero conflicts.
// unroll-1 on jt/kk contains the unroller (R6 lesson: hoisting caused spill).
__global__ __launch_bounds__(256, 2)
void sim_kernel(const unsigned char* __restrict__ fQ,
                float* __restrict__ Z, float* __restrict__ T01,
                float* __restrict__ D) {
  __shared__ unsigned char ldsA[4][128 * 128];  // 64 KB: full K, 4 chunk-planes
  __shared__ unsigned char ldsB[128 * 128];     // 16 KB

  const int tid = threadIdx.x;
  const int lane = tid & 63;
  const int w = tid >> 6;
  const int wm = w & 1;       // wave row strip (0/1) -> rows wm*64..
  const int wn = w >> 1;      // wave col strip (0/1) -> cols wn*64..
  const int bx = blockIdx.x, by = blockIdx.y;
  const int I0 = bx * 128;
  const int Jbase = by * 1024;

  // staging lane geometry: 8 rows x 8 slots(16B) per instruction.
  // slot b of row a sources global granule h(b^a), h(u)=2(u&3)+(u>>2).
  const int srow = lane >> 3;                 // 0..7
  const int sb = lane & 7;                    // dest slot
  const int su = sb ^ srow;
  const int sg = 2 * (su & 3) + (su >> 2);    // source granule
  const size_t sOff = (size_t)srow * ROWB + sg * 16;  // bytes

  // fragment-read lane geometry
  const int fr = lane & 15;   // M/N index within 16
  const int q = lane >> 4;    // quad -> k chunk of 32B
  const int swz = fr & 7;     // row&7 of the frag row

  // precomputed LDS frag base offsets (byte addresses)
  const int raRow = (wm * 64 + fr) * 128;
  const unsigned char* rbBase = ldsB + (wn * 64 + fr) * 128;
  const int off0 = (q ^ swz) * 16;        // slot holding granule 2q
  const int off1 = ((q + 4) ^ swz) * 16;  // slot holding granule 2q+1

  // ---- stage A once: wave w stages rows w*32..+31, all 4 K-chunks ----------
#pragma unroll
  for (int kk = 0; kk < 4; ++kk) {
    const unsigned char* gA = fQ + (size_t)(I0 + w * 32) * ROWB + kk * 128 + sOff;
    unsigned char* lA = ldsA[kk] + (w * 32) * 128;
#pragma unroll
    for (int rr = 0; rr < 32; rr += 8)
      load16_to_lds(gA + (size_t)rr * ROWB, lA + rr * 128);
  }
  // (first __syncthreads inside the kk loop below covers A readiness)

  float Zp[4][4];
#pragma unroll
  for (int m = 0; m < 4; ++m)
#pragma unroll
    for (int r = 0; r < 4; ++r) Zp[m][r] = 0.0f;

#pragma unroll 1
  for (int jt = 0; jt < 8; ++jt) {
    const int J0 = Jbase + jt * 128;
    f32x4 acc[4][4];
#pragma unroll
    for (int m = 0; m < 4; ++m)
#pragma unroll
      for (int n = 0; n < 4; ++n) acc[m][n] = (f32x4){0.f, 0.f, 0.f, 0.f};

#pragma unroll 1
    for (int kk = 0; kk < 4; ++kk) {
      const int k0 = kk * 128;  // byte offset into row
      {  // B: 128 rows, wave stages rows w*32..+31 (4 instrs)
        const unsigned char* gB = fQ + (size_t)(J0 + w * 32) * ROWB + k0 + sOff;
        unsigned char* lB = ldsB + (w * 32) * 128;
#pragma unroll
        for (int rr = 0; rr < 32; rr += 8)
          load16_to_lds(gB + (size_t)rr * ROWB, lB + rr * 128);
      }
      __syncthreads();

      const unsigned char* raBase = ldsA[kk] + raRow;
      i32x8 bv[4];
#pragma unroll
      for (int n = 0; n < 4; ++n) {
        const unsigned char* rb = rbBase + n * 16 * 128;
        int4 r0 = *(const int4*)(rb + off0);
        int4 r1 = *(const int4*)(rb + off1);
        bv[n] = (i32x8){r0.x, r0.y, r0.z, r0.w, r1.x, r1.y, r1.z, r1.w};
      }
#pragma unroll
      for (int mh = 0; mh < 2; ++mh) {  // m-split: av[2] live, not av[4]
        i32x8 av[2];
#pragma unroll
        for (int m = 0; m < 2; ++m) {
          const unsigned char* ra = raBase + (mh * 2 + m) * 16 * 128;
          int4 r0 = *(const int4*)(ra + off0);
          int4 r1 = *(const int4*)(ra + off1);
          av[m] = (i32x8){r0.x, r0.y, r0.z, r0.w, r1.x, r1.y, r1.z, r1.w};
        }
#pragma unroll
        for (int m = 0; m < 2; ++m)
#pragma unroll
          for (int n = 0; n < 4; ++n)
            acc[mh * 2 + m][n] = __builtin_amdgcn_mfma_scale_f32_16x16x128_f8f6f4(
                av[m], bv[n], acc[mh * 2 + m][n], 0, 0, 0, 127, 0, 127);
      }
      __syncthreads();
    }

    // capture sim[:,0] and sim[:,1] (cols 0,1: j-tile 0, wn==0, n==0, fr<2)
    if (by == 0 && jt == 0 && wn == 0 && fr < 2) {
#pragma unroll
      for (int m = 0; m < 4; ++m)
#pragma unroll
        for (int r = 0; r < 4; ++r) {
          const int row = I0 + wm * 64 + m * 16 + q * 4 + r;
          T01[row * 2 + fr] = acc[m][0][r] * INVT;
        }
    }

    // capture the computed diagonal dot (for exact-diag correction)
    if (by == (bx >> 3) && jt == (bx & 7)) {
#pragma unroll
      for (int m = 0; m < 4; ++m)
#pragma unroll
        for (int n = 0; n < 4; ++n) {
          const int col = J0 + wn * 64 + n * 16 + fr;
#pragma unroll
          for (int r = 0; r < 4; ++r) {
            const int row = I0 + wm * 64 + m * 16 + q * 4 + r;
            if (row == col) D[row] = acc[m][n][r];
          }
        }
    }

    // Z partials: exp((dot-1)/T) summed over this wave's 64 cols
#pragma unroll
    for (int m = 0; m < 4; ++m)
#pragma unroll
      for (int n = 0; n < 4; ++n)
#pragma unroll
        for (int r = 0; r < 4; ++r)
          Zp[m][r] += exp2f((acc[m][n][r] - 1.0f) * SCALE_LOG2);
  }

  // reduce Zp across the 16 col-lanes (low 4 lane bits), then atomicAdd
#pragma unroll
  for (int m = 0; m < 4; ++m)
#pragma unroll
    for (int r = 0; r < 4; ++r) {
      float v = Zp[m][r];
      v += __shfl_xor(v, 1);
      v += __shfl_xor(v, 2);
      v += __shfl_xor(v, 4);
      v += __shfl_xor(v, 8);
      if (fr == 0) atomicAdd(&Z[I0 + wm * 64 + m * 16 + q * 4 + r], v);
    }
}

// ---- K3: labels + exact-diagonal fixup + final loss reduction ---------------
// 1024 threads, 8 rows each, all loads batched/independent.
__global__ __launch_bounds__(1024)
void finalize_kernel(const float* __restrict__ Z,
                     const float* __restrict__ T01,
                     const float* __restrict__ D,
                     const int* __restrict__ ids,
                     const int* __restrict__ anchor,
                     float* __restrict__ out) {
  __shared__ float red[1024];
  const int t = threadIdx.x;
  const int anchor_id = ids[anchor[0]];
  const int sameLast = (ids[B_N - 1] == anchor_id);
  const int samePrev = (ids[B_N - 2] == anchor_id);
  int i[8], id[8];
  float z[8], d[8], t0[8], t1[8];
#pragma unroll
  for (int u = 0; u < 8; ++u) {
    i[u] = u * 1024 + t;
    z[u] = Z[i[u]];
    d[u] = D[i[u]];
    t0[u] = T01[i[u] * 2 + 0];
    t1[u] = T01[i[u] * 2 + 1];
    id[u] = ids[i[u]];
  }
  float sum = 0.0f;
#pragma unroll
  for (int u = 0; u < 8; ++u) {
    const int same_i = (id[u] == anchor_id);
    const int lab =
        (i[u] < B_N - 1) ? (same_i & sameLast) : (sameLast & samePrev);
    const float tt = lab ? t1[u] : t0[u];
    // replace quantized diag contribution with the exact value exp(0)=1
    const float Zc = z[u] - exp2f((d[u] - 1.0f) * SCALE_LOG2) + 1.0f;
    sum += tt - (INVT + logf(Zc));
  }
  red[t] = sum;
  __syncthreads();
  for (int off = 512; off > 0; off >>= 1) {
    if (t < off) red[t] += red[t + off];
    __syncthreads();
  }
  if (t == 0) out[0] = -red[0] / (float)B_N;
}

// ---------------------------------------------------------------------------
extern "C" void kernel_launch(void* const* d_in, const int* in_sizes, int n_in,
                              void* d_out, int out_size, void* d_ws, size_t ws_size,
                              hipStream_t stream) {
  const float* x = (const float*)d_in[0];
  const int* ids = (const int*)d_in[1];
  const int* anchor = (const int*)d_in[2];
  float* out = (float*)d_out;

  unsigned char* fQ = (unsigned char*)d_ws;                    // 4 MB fp8
  float* Z = (float*)((char*)d_ws + (size_t)B_N * ROWB);       // 32 KB
  float* T01 = Z + B_N;                                        // 64 KB
  float* D = T01 + 2 * B_N;                                    // 32 KB

  norm_kernel<<<B_N / 4, 256, 0, stream>>>(x, fQ, Z);
  sim_kernel<<<dim3(64, 8), 256, 0, stream>>>(fQ, Z, T01, D);
  finalize_kernel<<<1, 1024, 0, stream>>>(Z, T01, D, ids, anchor, out);
}